// Round 17
// baseline (431.535 us; speedup 1.0000x reference)
//
#include <hip/hip_runtime.h>
#include <math.h>

#define BB 8
#define CC 192
#define NN 3136            // 56*56
#define NR 25088           // BB*NN
#define C2 384
#define GI 96
#define KNN 9
#define NCHUNK 256
#define RPC 98             // 256*98 = 25088
#define EPS_BN 1e-5f

typedef unsigned short ushortT;
typedef unsigned int uintT;
typedef _Float16 f16x8 __attribute__((ext_vector_type(8)));
typedef float f32x4 __attribute__((ext_vector_type(4)));

static __device__ __forceinline__ ushortT f16b(_Float16 v) {
  union { _Float16 f; ushortT u; } x; x.f = v; return x.u;
}
static __device__ __forceinline__ float f16tof(ushortT u) {
  union { ushortT u; _Float16 f; } x; x.u = u; return (float)x.f;
}
// pack 11-bit local candidate idx into low mantissa bits of d (deterministic total order)
static __device__ __forceinline__ float packdi(float d, int cidx) {
  return __uint_as_float((__float_as_uint(d) & 0xFFFFF800u) | (uintT)cidx);
}
static __device__ __forceinline__ void split8(const float* vv, f16x8& hi, f16x8& lo) {
  #pragma unroll
  for (int e = 0; e < 8; ++e) {
    _Float16 hh = (_Float16)vv[e];
    hi[e] = hh;
    lo[e] = (_Float16)((vv[e] - (float)hh)*4096.f);
  }
}

// ---------------- fc1: fp32 (r2-validated) ----------------
__global__ __launch_bounds__(256) void k_fc1(const float* __restrict__ x,
        const float* __restrict__ w1, const float* __restrict__ b1,
        float* __restrict__ z) {
  __shared__ __align__(16) float Xs[32*68];
  __shared__ __align__(16) float Ws[32*68];
  int b = blockIdx.z, n0 = blockIdx.x*64, c0 = blockIdx.y*64;
  int tid = threadIdx.x;
  int tcol = tid & 15, trow = tid >> 4;
  float acc[4][4] = {};
  const float4* xf4 = (const float4*)x;
  const float4* wf4 = (const float4*)w1;
  for (int kb = 0; kb < 6; ++kb) {
    int k0 = kb*32;
    __syncthreads();
    #pragma unroll
    for (int s = 0; s < 2; ++s) {
      int q = tid + 256*s;
      int kk = q >> 4, nq = q & 15;
      ((float4*)Xs)[kk*17 + nq] = xf4[(size_t)(b*CC + k0 + kk)*784 + (n0>>2) + nq];
    }
    #pragma unroll
    for (int s = 0; s < 2; ++s) {
      int q = tid + 256*s;
      int cc = q >> 3, kq = q & 7;
      float4 v = wf4[(size_t)(c0 + cc)*48 + (k0>>2) + kq];
      Ws[(kq*4+0)*68 + cc] = v.x;
      Ws[(kq*4+1)*68 + cc] = v.y;
      Ws[(kq*4+2)*68 + cc] = v.z;
      Ws[(kq*4+3)*68 + cc] = v.w;
    }
    __syncthreads();
    #pragma unroll 8
    for (int kk = 0; kk < 32; ++kk) {
      float4 a4 = ((const float4*)Xs)[kk*17 + trow];
      float4 b4 = ((const float4*)Ws)[kk*17 + tcol];
      float av[4] = {a4.x,a4.y,a4.z,a4.w};
      float bv[4] = {b4.x,b4.y,b4.z,b4.w};
      #pragma unroll
      for (int i = 0; i < 4; ++i)
        #pragma unroll
        for (int j = 0; j < 4; ++j)
          acc[i][j] += av[i]*bv[j];
    }
  }
  float4 bias = ((const float4*)b1)[(c0>>2) + tcol];
  float bb4[4] = {bias.x,bias.y,bias.z,bias.w};
  #pragma unroll
  for (int i = 0; i < 4; ++i) {
    int n = n0 + trow*4 + i;
    float4 o;
    o.x = acc[i][0] + bb4[0]; o.y = acc[i][1] + bb4[1];
    o.z = acc[i][2] + bb4[2]; o.w = acc[i][3] + bb4[3];
    ((float4*)z)[(size_t)(b*NN + n)*48 + (c0>>2) + tcol] = o;
  }
}

// ---------------- BN stats: deterministic 2-stage ----------------
__global__ void k_stats_part(const float* __restrict__ src, int C, float* __restrict__ part) {
  int c = threadIdx.x;        // blockDim.x == C
  int chunk = blockIdx.x;     // 0..255
  float s = 0.f, ss = 0.f;
  const float* p = src + (size_t)chunk*RPC*C + c;
  for (int r = 0; r < RPC; ++r) {
    float v = p[(size_t)r*C];
    s += v; ss += v*v;
  }
  part[(size_t)chunk*C + c] = s;
  part[(size_t)(NCHUNK + chunk)*C + c] = ss;
}

// PARALLEL finalize: one block per channel, one thread per chunk (r15-validated, ~3us)
__global__ __launch_bounds__(256) void k_stats_fin(const float* __restrict__ part, int C,
      const float* __restrict__ g, const float* __restrict__ be,
      float* __restrict__ scale, float* __restrict__ shift) {
  int c = blockIdx.x;          // 0..C-1
  int t = threadIdx.x;         // 0..255 = chunk
  float s  = part[(size_t)t*C + c];
  float ss = part[(size_t)(NCHUNK + t)*C + c];
  #pragma unroll
  for (int o = 32; o; o >>= 1) { s += __shfl_xor(s, o); ss += __shfl_xor(ss, o); }
  __shared__ float sred[4], ssred[4];
  int w = t >> 6, lane = t & 63;
  if (lane == 0) { sred[w] = s; ssred[w] = ss; }
  __syncthreads();
  if (t == 0) {
    float s2  = (sred[0] + sred[1]) + (sred[2] + sred[3]);
    float ss2 = (ssred[0] + ssred[1]) + (ssred[2] + ssred[3]);
    float mu = s2 / (float)NR;
    float var = ss2/(float)NR - mu*mu;
    float rs = 1.0f / sqrtf(var + EPS_BN);
    float sc = g[c]*rs;
    scale[c] = sc;
    shift[c] = be[c] - mu*sc;
  }
}

// ---- generic fp32 -> f16 hi/lo pack (for weights) ----
__global__ void k_packw(const float* __restrict__ src, int n4,
                        ushortT* __restrict__ hi, ushortT* __restrict__ lo) {
  int i = blockIdx.x*256 + threadIdx.x;
  if (i >= n4) return;
  float4 v = ((const float4*)src)[i];
  float vv[4] = {v.x, v.y, v.z, v.w};
  ushortT hb[4], lb[4];
  #pragma unroll
  for (int t = 0; t < 4; ++t) {
    _Float16 hh = (_Float16)vv[t];
    float r = vv[t] - (float)hh;
    _Float16 ll = (_Float16)(r*4096.f);
    hb[t] = f16b(hh); lb[t] = f16b(ll);
  }
  ((uint2*)hi)[i] = make_uint2((uintT)hb[0] | ((uintT)hb[1]<<16), (uintT)hb[2] | ((uintT)hb[3]<<16));
  ((uint2*)lo)[i] = make_uint2((uintT)lb[0] | ((uintT)lb[1]<<16), (uintT)lb[2] | ((uintT)lb[3]<<16));
}

// ---- h = bn(z) in place; emit f16 split of f = h/||h|| (hi + lo*2^-12) and sqh = 0.5*sum f^2 ----
__global__ __launch_bounds__(256) void k_h_f(float* __restrict__ h,
      ushortT* __restrict__ fhi, ushortT* __restrict__ flo, float* __restrict__ sqh,
      const float* __restrict__ scale, const float* __restrict__ shift) {
  __shared__ __align__(16) float fbuf[4][192];
  int w = threadIdx.x >> 6, lane = threadIdx.x & 63;
  size_t row = (size_t)blockIdx.x*4 + w;
  float* hp = h + row*CC;
  float hv[3]; float s = 0.f;
  #pragma unroll
  for (int t = 0; t < 3; ++t) {
    int c = lane + 64*t;
    float v = hp[c]*scale[c] + shift[c];
    hv[t] = v; s += v*v;
  }
  #pragma unroll
  for (int o = 32; o; o >>= 1) s += __shfl_xor(s, o);
  float eta = fmaxf(sqrtf(s), 1e-12f);
  float fv[3]; float s2 = 0.f;
  #pragma unroll
  for (int t = 0; t < 3; ++t) { fv[t] = hv[t]/eta; s2 += fv[t]*fv[t]; }
  #pragma unroll
  for (int o = 32; o; o >>= 1) s2 += __shfl_xor(s2, o);
  #pragma unroll
  for (int t = 0; t < 3; ++t) {
    int c = lane + 64*t;
    hp[c] = hv[t];
    fbuf[w][c] = fv[t];
  }
  if (lane == 0) sqh[row] = 0.5f*s2;
  __syncthreads();
  if (threadIdx.x < 192) {
    int r = threadIdx.x / 48, q = threadIdx.x % 48;
    size_t grow = (size_t)blockIdx.x*4 + r;
    float4 v = *(float4*)&fbuf[r][q*4];
    _Float16 a0=(_Float16)v.x, a1=(_Float16)v.y, a2=(_Float16)v.z, a3=(_Float16)v.w;
    float r0=v.x-(float)a0, r1=v.y-(float)a1, r2=v.z-(float)a2, r3=v.w-(float)a3;
    _Float16 b0=(_Float16)(r0*4096.f), b1=(_Float16)(r1*4096.f);
    _Float16 b2=(_Float16)(r2*4096.f), b3=(_Float16)(r3*4096.f);
    uintT hi0 = (uintT)f16b(a0) | ((uintT)f16b(a1)<<16);
    uintT hi1 = (uintT)f16b(a2) | ((uintT)f16b(a3)<<16);
    uintT lo0 = (uintT)f16b(b0) | ((uintT)f16b(b1)<<16);
    uintT lo1 = (uintT)f16b(b2) | ((uintT)f16b(b3)<<16);
    ((uint2*)(fhi + grow*CC))[q] = make_uint2(hi0, hi1);
    ((uint2*)(flo + grow*CC))[q] = make_uint2(lo0, lo1);
  }
}

// ---- tier-1: approximate top-12 per (row, candidate-half) via hi-f16 MFMA ----
// Selection: batched Batcher-sort(8) + keep-top-12 bitonic merge (r16-validated).
__global__ __launch_bounds__(256) void k_knn12(const ushortT* __restrict__ fhi_,
    const float* __restrict__ sqh, int* __restrict__ idx12) {
  __shared__ __align__(16) f16x8 AHs[2][768];   // 2 buf x 32 cands x 24 units = 24 KB
  __shared__ float sqs[1568];                   // 6.25 KB
  int id = blockIdx.x;
  int b = id & 7, half = (id >> 3) & 1, rt = id >> 4;
  int tid = threadIdx.x, w = tid >> 6, lane = tid & 63;
  int l15 = lane & 15, kg = lane >> 4;          // kg = K-group 0..3

  const f16x8* FH = (const f16x8*)(fhi_ + (size_t)b*NN*CC);  // row stride 24 units
  int cbase = half*1568;
  const f16x8* FC = FH + (size_t)cbase*24;

  int soff[3];
  #pragma unroll
  for (int i = 0; i < 3; ++i) {
    int s = i*256 + tid;
    int rr = s/24, u = s - rr*24;
    soff[i] = rr*24 + (u ^ (rr&7));
  }
  #pragma unroll
  for (int i = 0; i < 3; ++i)
    __builtin_amdgcn_global_load_lds(
      (const __attribute__((address_space(1))) void*)(FC + soff[i]),
      (__attribute__((address_space(3))) void*)&AHs[0][i*256 + w*64], 16, 0, 0);

  for (int i = tid; i < 1568/4; i += 256)
    ((float4*)sqs)[i] = ((const float4*)(sqh + (size_t)b*NN + cbase))[i];

  int row = rt*64 + w*16 + l15;
  f16x8 Bh[6];
  #pragma unroll
  for (int ks = 0; ks < 6; ++ks)
    Bh[ks] = FH[(size_t)row*24 + ks*4 + kg];

  float PD[12];
  #pragma unroll
  for (int t = 0; t < 12; ++t) PD[t] = -3.0e38f;

  __syncthreads();   // chunk 0 staged (implicit vmcnt 0), sqs ready

  int buf = 0;
  for (int ct = 0; ct < 49; ++ct) {
    if (ct + 1 < 49) {
      #pragma unroll
      for (int i = 0; i < 3; ++i)
        __builtin_amdgcn_global_load_lds(
          (const __attribute__((address_space(1))) void*)(FC + (ct+1)*768 + soff[i]),
          (__attribute__((address_space(3))) void*)&AHs[buf^1][i*256 + w*64], 16, 0, 0);
    }
    f32x4 acc0 = {0.f,0.f,0.f,0.f}, acc1 = {0.f,0.f,0.f,0.f};
    #pragma unroll
    for (int ks = 0; ks < 6; ++ks) {
      int ub = ks*4 + kg;
      f16x8 a0 = AHs[buf][(     l15)*24 + (ub ^ (l15&7))];
      f16x8 a1 = AHs[buf][(16 + l15)*24 + (ub ^ (l15&7))];
      acc0 = __builtin_amdgcn_mfma_f32_16x16x32_f16(a0, Bh[ks], acc0, 0, 0, 0);
      acc1 = __builtin_amdgcn_mfma_f32_16x16x32_f16(a1, Bh[ks], acc1, 0, 0, 0);
    }
    int jbl = ct*32 + kg*4;
    float4 s0 = *(float4*)&sqs[jbl];
    float4 s1 = *(float4*)&sqs[jbl + 16];
    float S[8] = {acc0[0]-s0.x, acc0[1]-s0.y, acc0[2]-s0.z, acc0[3]-s0.w,
                  acc1[0]-s1.x, acc1[1]-s1.y, acc1[2]-s1.z, acc1[3]-s1.w};
    #pragma unroll
    for (int r = 0; r < 8; ++r)
      S[r] = packdi(S[r], jbl + (r&3) + ((r>>2)<<4));
#define CED(i,j) { float hi_ = fmaxf(S[i],S[j]), lo_ = fminf(S[i],S[j]); S[i]=hi_; S[j]=lo_; }
    CED(0,1) CED(2,3) CED(4,5) CED(6,7)
    CED(0,2) CED(1,3) CED(4,6) CED(5,7)
    CED(1,2) CED(5,6)
    CED(0,4) CED(1,5) CED(2,6) CED(3,7)
    CED(2,4) CED(3,5)
    CED(1,2) CED(3,4) CED(5,6)
#undef CED
    #pragma unroll
    for (int i = 0; i < 8; ++i) PD[i] = fmaxf(PD[i], S[i]);
#define CEA(i,j) { float lo_ = fminf(PD[i],PD[j]), hi_ = fmaxf(PD[i],PD[j]); PD[i]=lo_; PD[j]=hi_; }
    CEA(0,8) CEA(1,9) CEA(2,10) CEA(3,11)
    CEA(0,4) CEA(1,5) CEA(2,6) CEA(3,7)
    CEA(0,2) CEA(1,3) CEA(4,6) CEA(5,7) CEA(8,10) CEA(9,11)
    CEA(0,1) CEA(2,3) CEA(4,5) CEA(6,7) CEA(8,9) CEA(10,11)
#undef CEA
    __syncthreads();
    buf ^= 1;
  }

  // STAGED asymmetric merge: per stage, source lanes immutable; non-absorbers insert -inf (no-op).
  #pragma unroll
  for (int t = 0; t < 12; ++t) {
    float od = __shfl_xor(PD[t], 32);
    float od2 = (kg < 2) ? od : -3.0e38f;
    PD[0] = fmaxf(PD[0], od2);
    #pragma unroll
    for (int t2 = 0; t2 < 11; ++t2) {
      float a = PD[t2], c2 = PD[t2+1];
      PD[t2] = fminf(a, c2); PD[t2+1] = fmaxf(a, c2);
    }
  }
  #pragma unroll
  for (int t = 0; t < 12; ++t) {
    float od = __shfl_xor(PD[t], 16);
    float od2 = (kg == 0) ? od : -3.0e38f;
    PD[0] = fmaxf(PD[0], od2);
    #pragma unroll
    for (int t2 = 0; t2 < 11; ++t2) {
      float a = PD[t2], c2 = PD[t2+1];
      PD[t2] = fminf(a, c2); PD[t2+1] = fmaxf(a, c2);
    }
  }
  if (kg == 0) {
    size_t base = ((size_t)(b*NN + row)*2 + half)*12;
    #pragma unroll
    for (int t = 0; t < 12; ++t)
      idx12[base + t] = cbase + (int)(__float_as_uint(PD[t]) & 0x7FFu);
  }
}

// ---- tier-2: exact fp32 refine of 24 survivors -> top-9; 8-lane-group decomposition ----
// Wave = row. Group g8 (8 lanes) handles cands {g8, g8+8, g8+16}; lane covers 24 contiguous
// channels via 3x uint4 loads. 3-level group reduce; LDS broadcast; wave-uniform top-9 insert
// in JP order (identical semantics to r8-validated selection).
__global__ __launch_bounds__(256) void k_refine(const ushortT* __restrict__ fhi_,
    const ushortT* __restrict__ flo_, const float* __restrict__ sqh,
    const int* __restrict__ idx12, int* __restrict__ idxg) {
  __shared__ float Ds[4][24];
  int id = blockIdx.x;
  int b = id & 7, rq = id >> 3;
  int w = threadIdx.x >> 6, lane = threadIdx.x & 63;
  int g8 = lane >> 3, l8 = lane & 7;
  int row = rq*4 + w;
  const ushortT* FHb = fhi_ + (size_t)b*NN*CC;
  const ushortT* FLb = flo_ + (size_t)b*NN*CC;

  // row vector: 24 contiguous channels per lane
  float rv[24];
  {
    const uint4* ph = (const uint4*)(FHb + (size_t)row*CC + l8*24);
    const uint4* pl = (const uint4*)(FLb + (size_t)row*CC + l8*24);
    #pragma unroll
    for (int i = 0; i < 3; ++i) {
      uint4 qh = ph[i], ql = pl[i];
      f16x8 vh = *(f16x8*)&qh, vl = *(f16x8*)&ql;
      #pragma unroll
      for (int e = 0; e < 8; ++e)
        rv[i*8+e] = (float)vh[e] + (float)vl[e]*2.44140625e-4f;
    }
  }
  const int* JP = idx12 + (size_t)(b*NN + row)*24;
  int J[24];
  #pragma unroll
  for (int q = 0; q < 24; ++q) J[q] = JP[q];

  #pragma unroll
  for (int p = 0; p < 3; ++p) {
    int q = g8 + p*8;
    int j = J[q];
    const uint4* ch = (const uint4*)(FHb + (size_t)j*CC + l8*24);
    const uint4* cl = (const uint4*)(FLb + (size_t)j*CC + l8*24);
    float s = 0.f;
    #pragma unroll
    for (int i = 0; i < 3; ++i) {
      uint4 qh = ch[i], ql = cl[i];
      f16x8 vh = *(f16x8*)&qh, vl = *(f16x8*)&ql;
      #pragma unroll
      for (int e = 0; e < 8; ++e) {
        float cv = (float)vh[e] + (float)vl[e]*2.44140625e-4f;
        s = fmaf(rv[i*8+e], cv, s);
      }
    }
    s += __shfl_xor(s, 1);
    s += __shfl_xor(s, 2);
    s += __shfl_xor(s, 4);
    if (l8 == 0) Ds[w][q] = s - sqh[(size_t)b*NN + j];
  }
  __syncthreads();   // per-wave LDS slab visible (also orders cross-wave timeline; harmless)

  float TD[9]; int TI[9];
  #pragma unroll
  for (int t = 0; t < 9; ++t) { TD[t] = -3.0e38f; TI[t] = 0x7fffffff; }
  #pragma unroll
  for (int q = 0; q < 24; ++q) {
    float d = Ds[w][q]; int j = J[q];
    bool ins = (d > TD[0]) || (d == TD[0] && j < TI[0]);
    if (ins) {   // wave-uniform branch
      TD[0] = d; TI[0] = j;
      #pragma unroll
      for (int t = 0; t < 8; ++t) {
        bool sw = (TD[t] > TD[t+1]) || (TD[t] == TD[t+1] && TI[t] < TI[t+1]);
        if (sw) {
          float td = TD[t]; TD[t] = TD[t+1]; TD[t+1] = td;
          int ti = TI[t]; TI[t] = TI[t+1]; TI[t+1] = ti;
        }
      }
    }
  }
  if (lane == 0) {
    size_t base = (size_t)(b*NN + row)*KNN;
    #pragma unroll
    for (int t = 0; t < KNN; ++t) idxg[base + t] = TI[t];
  }
}

// ---- gather neighbors, rel = max_k h[idx_k] - h, interleave fp32 feat ----
__global__ __launch_bounds__(256) void k_gather(const float* __restrict__ h,
    const int* __restrict__ idxg, float* __restrict__ feat) {
  int w = threadIdx.x >> 6, lane = threadIdx.x & 63;
  size_t rg = (size_t)blockIdx.x*4 + w;
  int b = (int)(rg / NN);
  int n = (int)(rg % NN);
  const float* hb = h + (size_t)b*NN*CC;
  int j[KNN];
  #pragma unroll
  for (int t = 0; t < KNN; ++t) j[t] = idxg[rg*KNN + t];
  float2* featp = (float2*)feat;
  #pragma unroll
  for (int t = 0; t < 3; ++t) {
    int c = lane + 64*t;
    float self = hb[(size_t)n*CC + c];
    float m = -3.0e38f;
    #pragma unroll
    for (int k = 0; k < KNN; ++k) m = fmaxf(m, hb[(size_t)j[k]*CC + c]);
    featp[rg*CC + c] = make_float2(self, m - self);
  }
}

// ---- grouped conv via f16-split MFMA; fp32 feat in, B-frags converted on the fly; in-place y ----
__global__ __launch_bounds__(256) void k_gconv(float* __restrict__ feat,
    const ushortT* __restrict__ wgh, const ushortT* __restrict__ wgl,
    const float* __restrict__ bgc, float* __restrict__ y) {
  int rt = blockIdx.x, g = blockIdx.y;
  int tid = threadIdx.x, w = tid >> 6, lane = tid & 63;
  int l15 = lane & 15, kg = lane >> 4;
  int row = rt*64 + w*16 + l15;
  const float4* F4 = (const float4*)feat;
  const f16x8* AH  = (const f16x8*)wgh;    // weight row (g*96+o), stride 12 units
  const f16x8* AL  = (const f16x8*)wgl;
  f16x8 Bh[3], Bl[3];
  #pragma unroll
  for (int ks = 0; ks < 3; ++ks) {
    float4 v0 = F4[(size_t)row*96 + g*24 + ks*8 + kg*2];
    float4 v1 = F4[(size_t)row*96 + g*24 + ks*8 + kg*2 + 1];
    float vv[8] = {v0.x,v0.y,v0.z,v0.w,v1.x,v1.y,v1.z,v1.w};
    split8(vv, Bh[ks], Bl[ks]);
  }
  #pragma unroll 3
  for (int nt = 0; nt < 6; ++nt) {
    f32x4 hh = {0.f,0.f,0.f,0.f}, hl = {0.f,0.f,0.f,0.f}, lh = {0.f,0.f,0.f,0.f};
    #pragma unroll
    for (int ks = 0; ks < 3; ++ks) {
      size_t au = (size_t)(g*GI + nt*16 + l15)*12 + ks*4 + kg;
      f16x8 Ah = AH[au], Al = AL[au];
      hh = __builtin_amdgcn_mfma_f32_16x16x32_f16(Ah, Bh[ks], hh, 0, 0, 0);
      hl = __builtin_amdgcn_mfma_f32_16x16x32_f16(Ah, Bl[ks], hl, 0, 0, 0);
      lh = __builtin_amdgcn_mfma_f32_16x16x32_f16(Al, Bh[ks], lh, 0, 0, 0);
    }
    float4 bias = ((const float4*)bgc)[g*24 + nt*4 + kg];
    float bb[4] = {bias.x, bias.y, bias.z, bias.w};
    float ov[4];
    #pragma unroll
    for (int r = 0; r < 4; ++r)
      ov[r] = fmaf(hl[r] + lh[r], 2.44140625e-4f, hh[r]) + bb[r];
    float4 o; o.x = ov[0]; o.y = ov[1]; o.z = ov[2]; o.w = ov[3];
    ((float4*)y)[(size_t)row*96 + g*24 + nt*4 + kg] = o;
  }
}

// ---- bn + exact gelu: read fp32 y, emit full-size f16 hi/lo packs for fc2 ----
__global__ void k_bn_gelu(const float* __restrict__ y, ushortT* __restrict__ y2hi,
    ushortT* __restrict__ y2lo, const float* __restrict__ scale,
    const float* __restrict__ shift) {
  size_t i = (size_t)blockIdx.x*blockDim.x + threadIdx.x;  // float4 index
  float4 v = ((const float4*)y)[i];
  int c4 = (int)(i % 96);
  float4 sc = ((const float4*)scale)[c4], sh = ((const float4*)shift)[c4];
  float vv[4] = {v.x*sc.x+sh.x, v.y*sc.y+sh.y, v.z*sc.z+sh.z, v.w*sc.w+sh.w};
  ushortT hb[4], lb[4];
  #pragma unroll
  for (int t = 0; t < 4; ++t) {
    float g = 0.5f*vv[t]*(1.0f + erff(vv[t]*0.70710678118654752440f));
    _Float16 hh = (_Float16)g;
    float r = g - (float)hh;
    hb[t] = f16b(hh); lb[t] = f16b((_Float16)(r*4096.f));
  }
  ((uint2*)y2hi)[i] = make_uint2((uintT)hb[0] | ((uintT)hb[1]<<16), (uintT)hb[2] | ((uintT)hb[3]<<16));
  ((uint2*)y2lo)[i] = make_uint2((uintT)lb[0] | ((uintT)lb[1]<<16), (uintT)lb[2] | ((uintT)lb[3]<<16));
}

// ---- fc2 via f16-split MFMA ----
__global__ __launch_bounds__(256) void k_fc2(const ushortT* __restrict__ y2hi,
    const ushortT* __restrict__ y2lo, const ushortT* __restrict__ w2h,
    const ushortT* __restrict__ w2l, const float* __restrict__ b2, float* __restrict__ op) {
  int rt = blockIdx.x;
  int tid = threadIdx.x, w = tid >> 6, lane = tid & 63;
  int l15 = lane & 15, kg = lane >> 4;
  int row = rt*64 + w*16 + l15;
  const f16x8* YH = (const f16x8*)y2hi;   // row stride 48 units
  const f16x8* YL = (const f16x8*)y2lo;
  const f16x8* AH = (const f16x8*)w2h;    // row (out-col) stride 48 units
  const f16x8* AL = (const f16x8*)w2l;
  f16x8 Bh[12], Bl[12];
  #pragma unroll
  for (int ks = 0; ks < 12; ++ks) {
    size_t u = (size_t)row*48 + ks*4 + kg;
    Bh[ks] = YH[u]; Bl[ks] = YL[u];
  }
  #pragma unroll 4
  for (int nt = 0; nt < 12; ++nt) {
    f32x4 hh = {0.f,0.f,0.f,0.f}, hl = {0.f,0.f,0.f,0.f}, lh = {0.f,0.f,0.f,0.f};
    #pragma unroll
    for (int ks = 0; ks < 12; ++ks) {
      size_t au = (size_t)(nt*16 + l15)*48 + ks*4 + kg;
      f16x8 Ah = AH[au], Al = AL[au];
      hh = __builtin_amdgcn_mfma_f32_16x16x32_f16(Ah, Bh[ks], hh, 0, 0, 0);
      hl = __builtin_amdgcn_mfma_f32_16x16x32_f16(Ah, Bl[ks], hl, 0, 0, 0);
      lh = __builtin_amdgcn_mfma_f32_16x16x32_f16(Al, Bh[ks], lh, 0, 0, 0);
    }
    float4 bias = ((const float4*)b2)[nt*4 + kg];
    float bb[4] = {bias.x, bias.y, bias.z, bias.w};
    float ov[4];
    #pragma unroll
    for (int r = 0; r < 4; ++r)
      ov[r] = fmaf(hl[r] + lh[r], 2.44140625e-4f, hh[r]) + bb[r];
    float4 o; o.x = ov[0]; o.y = ov[1]; o.z = ov[2]; o.w = ov[3];
    ((float4*)op)[(size_t)row*48 + nt*4 + kg] = o;
  }
}

// ---------------- final bn + residual + transpose to (B,C,N) ----------------
__global__ __launch_bounds__(256) void k_final(const float* __restrict__ op,
    const float* __restrict__ x, const float* __restrict__ scale,
    const float* __restrict__ shift, float* __restrict__ out) {
  __shared__ float t[32][33];
  int n0 = blockIdx.x*32, c0 = blockIdx.y*32, b = blockIdx.z;
  int tx = threadIdx.x, ty = threadIdx.y;
  #pragma unroll
  for (int s = 0; s < 4; ++s) {
    int r = ty + 8*s;
    int c = c0 + tx;
    t[r][tx] = op[((size_t)b*NN + n0 + r)*CC + c]*scale[c] + shift[c];
  }
  __syncthreads();
  #pragma unroll
  for (int s = 0; s < 4; ++s) {
    int c = ty + 8*s;
    size_t o = ((size_t)b*CC + c0 + c)*NN + n0 + tx;
    out[o] = t[tx][c] + x[o];
  }
}

extern "C" void kernel_launch(void* const* d_in, const int* in_sizes, int n_in,
                              void* d_out, int out_size, void* d_ws, size_t ws_size,
                              hipStream_t stream) {
  (void)in_sizes; (void)n_in; (void)out_size; (void)ws_size;
  const float* x   = (const float*)d_in[0];
  const float* w1  = (const float*)d_in[1];
  const float* b1  = (const float*)d_in[2];
  const float* g1  = (const float*)d_in[3];
  const float* be1 = (const float*)d_in[4];
  const float* wgc = (const float*)d_in[5];
  const float* bgc = (const float*)d_in[6];
  const float* g2  = (const float*)d_in[7];
  const float* be2 = (const float*)d_in[8];
  const float* w2  = (const float*)d_in[9];
  const float* b2  = (const float*)d_in[10];
  const float* g3  = (const float*)d_in[11];
  const float* be3 = (const float*)d_in[12];
  float* ws = (float*)d_ws;

  // Workspace layout (floats) — identical to round 15/16:
  float* h      = ws;
  ushortT* fhi  = (ushortT*)(ws + 4816896);
  ushortT* flo  = (ushortT*)(ws + 7225344);
  float* feat   = ws + 4816896;
  float* y      = feat;                        // in-place
  ushortT* y2hi = (ushortT*)ws;                // A
  ushortT* y2lo = (ushortT*)(ws + 14450688);   // C
  float* op     = ws + 4816896;
  float* sqh    = ws + 14450688;
  int*   idxg   = (int*)(ws + 14475776);
  int*   idx12  = (int*)(ws + 14701568);       // ends 15303680 < 19267584
  float* st     = ws + 19267584;               // 1536
  float* part   = ws + 19269120;               // 196608
  ushortT* w2h  = (ushortT*)(ws + 19465728);   // 73728 ushorts
  ushortT* w2l  = (ushortT*)(ws + 19502592);
  ushortT* wgh  = (ushortT*)(ws + 19539456);   // 36864 ushorts
  ushortT* wgl  = (ushortT*)(ws + 19557888);   // end 19576320 floats = 78.3 MB
  float* sc1 = st;        float* sh1 = st + 192;
  float* sc2 = st + 384;  float* sh2 = st + 768;
  float* sc3 = st + 1152; float* sh3 = st + 1344;
  float* out = (float*)d_out;

  k_packw<<<72, 256, 0, stream>>>(w2, 18432, w2h, w2l);
  k_packw<<<36, 256, 0, stream>>>(wgc, 9216, wgh, wgl);
  k_fc1<<<dim3(49,3,8), 256, 0, stream>>>(x, w1, b1, h);
  k_stats_part<<<NCHUNK, CC, 0, stream>>>(h, CC, part);
  k_stats_fin<<<CC, 256, 0, stream>>>(part, CC, g1, be1, sc1, sh1);
  k_h_f<<<NR/4, 256, 0, stream>>>(h, fhi, flo, sqh, sc1, sh1);
  k_knn12<<<dim3(784), 256, 0, stream>>>(fhi, sqh, idx12);
  k_refine<<<dim3(6272), 256, 0, stream>>>(fhi, flo, sqh, idx12, idxg);
  k_gather<<<NR/4, 256, 0, stream>>>(h, idxg, feat);
  k_gconv<<<dim3(392,4), 256, 0, stream>>>(feat, wgh, wgl, bgc, y);   // in-place
  k_stats_part<<<NCHUNK, C2, 0, stream>>>(y, C2, part);
  k_stats_fin<<<C2, 256, 0, stream>>>(part, C2, g2, be2, sc2, sh2);
  k_bn_gelu<<<9408, 256, 0, stream>>>(y, y2hi, y2lo, sc2, sh2);
  k_fc2<<<392, 256, 0, stream>>>(y2hi, y2lo, w2h, w2l, b2, op);
  k_stats_part<<<NCHUNK, CC, 0, stream>>>(op, CC, part);
  k_stats_fin<<<CC, 256, 0, stream>>>(part, CC, g3, be3, sc3, sh3);
  k_final<<<dim3(98,6,8), dim3(32,8), 0, stream>>>(op, x, sc3, sh3, out);
}

// Round 18
// 419.253 us; speedup vs baseline: 1.0293x; 1.0293x over previous
//
#include <hip/hip_runtime.h>
#include <math.h>

#define BB 8
#define CC 192
#define NN 3136            // 56*56
#define NR 25088           // BB*NN
#define C2 384
#define GI 96
#define KNN 9
#define NCHUNK 256
#define RPC 98             // 256*98 = 25088
#define EPS_BN 1e-5f

typedef unsigned short ushortT;
typedef unsigned int uintT;
typedef _Float16 f16x8 __attribute__((ext_vector_type(8)));
typedef float f32x4 __attribute__((ext_vector_type(4)));

static __device__ __forceinline__ ushortT f16b(_Float16 v) {
  union { _Float16 f; ushortT u; } x; x.f = v; return x.u;
}
static __device__ __forceinline__ float f16tof(ushortT u) {
  union { ushortT u; _Float16 f; } x; x.u = u; return (float)x.f;
}
// pack 11-bit local candidate idx into low mantissa bits of d (deterministic total order)
static __device__ __forceinline__ float packdi(float d, int cidx) {
  return __uint_as_float((__float_as_uint(d) & 0xFFFFF800u) | (uintT)cidx);
}
static __device__ __forceinline__ void split8(const float* vv, f16x8& hi, f16x8& lo) {
  #pragma unroll
  for (int e = 0; e < 8; ++e) {
    _Float16 hh = (_Float16)vv[e];
    hi[e] = hh;
    lo[e] = (_Float16)((vv[e] - (float)hh)*4096.f);
  }
}

// ---------------- fc1: fp32 (r2-validated) ----------------
__global__ __launch_bounds__(256) void k_fc1(const float* __restrict__ x,
        const float* __restrict__ w1, const float* __restrict__ b1,
        float* __restrict__ z) {
  __shared__ __align__(16) float Xs[32*68];
  __shared__ __align__(16) float Ws[32*68];
  int b = blockIdx.z, n0 = blockIdx.x*64, c0 = blockIdx.y*64;
  int tid = threadIdx.x;
  int tcol = tid & 15, trow = tid >> 4;
  float acc[4][4] = {};
  const float4* xf4 = (const float4*)x;
  const float4* wf4 = (const float4*)w1;
  for (int kb = 0; kb < 6; ++kb) {
    int k0 = kb*32;
    __syncthreads();
    #pragma unroll
    for (int s = 0; s < 2; ++s) {
      int q = tid + 256*s;
      int kk = q >> 4, nq = q & 15;
      ((float4*)Xs)[kk*17 + nq] = xf4[(size_t)(b*CC + k0 + kk)*784 + (n0>>2) + nq];
    }
    #pragma unroll
    for (int s = 0; s < 2; ++s) {
      int q = tid + 256*s;
      int cc = q >> 3, kq = q & 7;
      float4 v = wf4[(size_t)(c0 + cc)*48 + (k0>>2) + kq];
      Ws[(kq*4+0)*68 + cc] = v.x;
      Ws[(kq*4+1)*68 + cc] = v.y;
      Ws[(kq*4+2)*68 + cc] = v.z;
      Ws[(kq*4+3)*68 + cc] = v.w;
    }
    __syncthreads();
    #pragma unroll 8
    for (int kk = 0; kk < 32; ++kk) {
      float4 a4 = ((const float4*)Xs)[kk*17 + trow];
      float4 b4 = ((const float4*)Ws)[kk*17 + tcol];
      float av[4] = {a4.x,a4.y,a4.z,a4.w};
      float bv[4] = {b4.x,b4.y,b4.z,b4.w};
      #pragma unroll
      for (int i = 0; i < 4; ++i)
        #pragma unroll
        for (int j = 0; j < 4; ++j)
          acc[i][j] += av[i]*bv[j];
    }
  }
  float4 bias = ((const float4*)b1)[(c0>>2) + tcol];
  float bb4[4] = {bias.x,bias.y,bias.z,bias.w};
  #pragma unroll
  for (int i = 0; i < 4; ++i) {
    int n = n0 + trow*4 + i;
    float4 o;
    o.x = acc[i][0] + bb4[0]; o.y = acc[i][1] + bb4[1];
    o.z = acc[i][2] + bb4[2]; o.w = acc[i][3] + bb4[3];
    ((float4*)z)[(size_t)(b*NN + n)*48 + (c0>>2) + tcol] = o;
  }
}

// ---------------- BN stats: deterministic 2-stage ----------------
__global__ void k_stats_part(const float* __restrict__ src, int C, float* __restrict__ part) {
  int c = threadIdx.x;        // blockDim.x == C
  int chunk = blockIdx.x;     // 0..255
  float s = 0.f, ss = 0.f;
  const float* p = src + (size_t)chunk*RPC*C + c;
  for (int r = 0; r < RPC; ++r) {
    float v = p[(size_t)r*C];
    s += v; ss += v*v;
  }
  part[(size_t)chunk*C + c] = s;
  part[(size_t)(NCHUNK + chunk)*C + c] = ss;
}

// PARALLEL finalize: one block per channel, one thread per chunk (r15-validated, ~3us)
__global__ __launch_bounds__(256) void k_stats_fin(const float* __restrict__ part, int C,
      const float* __restrict__ g, const float* __restrict__ be,
      float* __restrict__ scale, float* __restrict__ shift) {
  int c = blockIdx.x;          // 0..C-1
  int t = threadIdx.x;         // 0..255 = chunk
  float s  = part[(size_t)t*C + c];
  float ss = part[(size_t)(NCHUNK + t)*C + c];
  #pragma unroll
  for (int o = 32; o; o >>= 1) { s += __shfl_xor(s, o); ss += __shfl_xor(ss, o); }
  __shared__ float sred[4], ssred[4];
  int w = t >> 6, lane = t & 63;
  if (lane == 0) { sred[w] = s; ssred[w] = ss; }
  __syncthreads();
  if (t == 0) {
    float s2  = (sred[0] + sred[1]) + (sred[2] + sred[3]);
    float ss2 = (ssred[0] + ssred[1]) + (ssred[2] + ssred[3]);
    float mu = s2 / (float)NR;
    float var = ss2/(float)NR - mu*mu;
    float rs = 1.0f / sqrtf(var + EPS_BN);
    float sc = g[c]*rs;
    scale[c] = sc;
    shift[c] = be[c] - mu*sc;
  }
}

// ---- merged weight pack: w2 (18432 float4) + wgc (9216 float4) in one launch ----
__global__ void k_packw2(const float* __restrict__ w2, const float* __restrict__ wgc,
    ushortT* __restrict__ w2h, ushortT* __restrict__ w2l,
    ushortT* __restrict__ wgh, ushortT* __restrict__ wgl) {
  int i = blockIdx.x*256 + threadIdx.x;
  const float* src; ushortT* hi; ushortT* lo; int k;
  if (i < 18432)       { src = w2;  hi = w2h; lo = w2l; k = i; }
  else if (i < 27648)  { src = wgc; hi = wgh; lo = wgl; k = i - 18432; }
  else return;
  float4 v = ((const float4*)src)[k];
  float vv[4] = {v.x, v.y, v.z, v.w};
  ushortT hb[4], lb[4];
  #pragma unroll
  for (int t = 0; t < 4; ++t) {
    _Float16 hh = (_Float16)vv[t];
    float r = vv[t] - (float)hh;
    hb[t] = f16b(hh); lb[t] = f16b((_Float16)(r*4096.f));
  }
  ((uint2*)hi)[k] = make_uint2((uintT)hb[0] | ((uintT)hb[1]<<16), (uintT)hb[2] | ((uintT)hb[3]<<16));
  ((uint2*)lo)[k] = make_uint2((uintT)lb[0] | ((uintT)lb[1]<<16), (uintT)lb[2] | ((uintT)lb[3]<<16));
}

// ---- h = bn(z) in place; emit f16 split of f = h/||h|| (hi + lo*2^-12) and sqh = 0.5*sum f^2 ----
__global__ __launch_bounds__(256) void k_h_f(float* __restrict__ h,
      ushortT* __restrict__ fhi, ushortT* __restrict__ flo, float* __restrict__ sqh,
      const float* __restrict__ scale, const float* __restrict__ shift) {
  __shared__ __align__(16) float fbuf[4][192];
  int w = threadIdx.x >> 6, lane = threadIdx.x & 63;
  size_t row = (size_t)blockIdx.x*4 + w;
  float* hp = h + row*CC;
  float hv[3]; float s = 0.f;
  #pragma unroll
  for (int t = 0; t < 3; ++t) {
    int c = lane + 64*t;
    float v = hp[c]*scale[c] + shift[c];
    hv[t] = v; s += v*v;
  }
  #pragma unroll
  for (int o = 32; o; o >>= 1) s += __shfl_xor(s, o);
  float eta = fmaxf(sqrtf(s), 1e-12f);
  float fv[3]; float s2 = 0.f;
  #pragma unroll
  for (int t = 0; t < 3; ++t) { fv[t] = hv[t]/eta; s2 += fv[t]*fv[t]; }
  #pragma unroll
  for (int o = 32; o; o >>= 1) s2 += __shfl_xor(s2, o);
  #pragma unroll
  for (int t = 0; t < 3; ++t) {
    int c = lane + 64*t;
    hp[c] = hv[t];
    fbuf[w][c] = fv[t];
  }
  if (lane == 0) sqh[row] = 0.5f*s2;
  __syncthreads();
  if (threadIdx.x < 192) {
    int r = threadIdx.x / 48, q = threadIdx.x % 48;
    size_t grow = (size_t)blockIdx.x*4 + r;
    float4 v = *(float4*)&fbuf[r][q*4];
    _Float16 a0=(_Float16)v.x, a1=(_Float16)v.y, a2=(_Float16)v.z, a3=(_Float16)v.w;
    float r0=v.x-(float)a0, r1=v.y-(float)a1, r2=v.z-(float)a2, r3=v.w-(float)a3;
    _Float16 b0=(_Float16)(r0*4096.f), b1=(_Float16)(r1*4096.f);
    _Float16 b2=(_Float16)(r2*4096.f), b3=(_Float16)(r3*4096.f);
    uintT hi0 = (uintT)f16b(a0) | ((uintT)f16b(a1)<<16);
    uintT hi1 = (uintT)f16b(a2) | ((uintT)f16b(a3)<<16);
    uintT lo0 = (uintT)f16b(b0) | ((uintT)f16b(b1)<<16);
    uintT lo1 = (uintT)f16b(b2) | ((uintT)f16b(b3)<<16);
    ((uint2*)(fhi + grow*CC))[q] = make_uint2(hi0, hi1);
    ((uint2*)(flo + grow*CC))[q] = make_uint2(lo0, lo1);
  }
}

// ---- tier-1: approximate top-12 per (row, candidate-half) via hi-f16 MFMA ----
// Selection: batched Batcher-sort(8) + keep-top-12 bitonic merge (r16-validated).
__global__ __launch_bounds__(256) void k_knn12(const ushortT* __restrict__ fhi_,
    const float* __restrict__ sqh, int* __restrict__ idx12) {
  __shared__ __align__(16) f16x8 AHs[2][768];   // 2 buf x 32 cands x 24 units = 24 KB
  __shared__ float sqs[1568];                   // 6.25 KB
  int id = blockIdx.x;
  int b = id & 7, half = (id >> 3) & 1, rt = id >> 4;
  int tid = threadIdx.x, w = tid >> 6, lane = tid & 63;
  int l15 = lane & 15, kg = lane >> 4;          // kg = K-group 0..3

  const f16x8* FH = (const f16x8*)(fhi_ + (size_t)b*NN*CC);  // row stride 24 units
  int cbase = half*1568;
  const f16x8* FC = FH + (size_t)cbase*24;

  int soff[3];
  #pragma unroll
  for (int i = 0; i < 3; ++i) {
    int s = i*256 + tid;
    int rr = s/24, u = s - rr*24;
    soff[i] = rr*24 + (u ^ (rr&7));
  }
  #pragma unroll
  for (int i = 0; i < 3; ++i)
    __builtin_amdgcn_global_load_lds(
      (const __attribute__((address_space(1))) void*)(FC + soff[i]),
      (__attribute__((address_space(3))) void*)&AHs[0][i*256 + w*64], 16, 0, 0);

  for (int i = tid; i < 1568/4; i += 256)
    ((float4*)sqs)[i] = ((const float4*)(sqh + (size_t)b*NN + cbase))[i];

  int row = rt*64 + w*16 + l15;
  f16x8 Bh[6];
  #pragma unroll
  for (int ks = 0; ks < 6; ++ks)
    Bh[ks] = FH[(size_t)row*24 + ks*4 + kg];

  float PD[12];
  #pragma unroll
  for (int t = 0; t < 12; ++t) PD[t] = -3.0e38f;

  __syncthreads();   // chunk 0 staged (implicit vmcnt 0), sqs ready

  int buf = 0;
  for (int ct = 0; ct < 49; ++ct) {
    if (ct + 1 < 49) {
      #pragma unroll
      for (int i = 0; i < 3; ++i)
        __builtin_amdgcn_global_load_lds(
          (const __attribute__((address_space(1))) void*)(FC + (ct+1)*768 + soff[i]),
          (__attribute__((address_space(3))) void*)&AHs[buf^1][i*256 + w*64], 16, 0, 0);
    }
    f32x4 acc0 = {0.f,0.f,0.f,0.f}, acc1 = {0.f,0.f,0.f,0.f};
    #pragma unroll
    for (int ks = 0; ks < 6; ++ks) {
      int ub = ks*4 + kg;
      f16x8 a0 = AHs[buf][(     l15)*24 + (ub ^ (l15&7))];
      f16x8 a1 = AHs[buf][(16 + l15)*24 + (ub ^ (l15&7))];
      acc0 = __builtin_amdgcn_mfma_f32_16x16x32_f16(a0, Bh[ks], acc0, 0, 0, 0);
      acc1 = __builtin_amdgcn_mfma_f32_16x16x32_f16(a1, Bh[ks], acc1, 0, 0, 0);
    }
    int jbl = ct*32 + kg*4;
    float4 s0 = *(float4*)&sqs[jbl];
    float4 s1 = *(float4*)&sqs[jbl + 16];
    float S[8] = {acc0[0]-s0.x, acc0[1]-s0.y, acc0[2]-s0.z, acc0[3]-s0.w,
                  acc1[0]-s1.x, acc1[1]-s1.y, acc1[2]-s1.z, acc1[3]-s1.w};
    #pragma unroll
    for (int r = 0; r < 8; ++r)
      S[r] = packdi(S[r], jbl + (r&3) + ((r>>2)<<4));
#define CED(i,j) { float hi_ = fmaxf(S[i],S[j]), lo_ = fminf(S[i],S[j]); S[i]=hi_; S[j]=lo_; }
    CED(0,1) CED(2,3) CED(4,5) CED(6,7)
    CED(0,2) CED(1,3) CED(4,6) CED(5,7)
    CED(1,2) CED(5,6)
    CED(0,4) CED(1,5) CED(2,6) CED(3,7)
    CED(2,4) CED(3,5)
    CED(1,2) CED(3,4) CED(5,6)
#undef CED
    #pragma unroll
    for (int i = 0; i < 8; ++i) PD[i] = fmaxf(PD[i], S[i]);
#define CEA(i,j) { float lo_ = fminf(PD[i],PD[j]), hi_ = fmaxf(PD[i],PD[j]); PD[i]=lo_; PD[j]=hi_; }
    CEA(0,8) CEA(1,9) CEA(2,10) CEA(3,11)
    CEA(0,4) CEA(1,5) CEA(2,6) CEA(3,7)
    CEA(0,2) CEA(1,3) CEA(4,6) CEA(5,7) CEA(8,10) CEA(9,11)
    CEA(0,1) CEA(2,3) CEA(4,5) CEA(6,7) CEA(8,9) CEA(10,11)
#undef CEA
    __syncthreads();
    buf ^= 1;
  }

  // STAGED asymmetric merge: per stage, source lanes immutable; non-absorbers insert -inf (no-op).
  #pragma unroll
  for (int t = 0; t < 12; ++t) {
    float od = __shfl_xor(PD[t], 32);
    float od2 = (kg < 2) ? od : -3.0e38f;
    PD[0] = fmaxf(PD[0], od2);
    #pragma unroll
    for (int t2 = 0; t2 < 11; ++t2) {
      float a = PD[t2], c2 = PD[t2+1];
      PD[t2] = fminf(a, c2); PD[t2+1] = fmaxf(a, c2);
    }
  }
  #pragma unroll
  for (int t = 0; t < 12; ++t) {
    float od = __shfl_xor(PD[t], 16);
    float od2 = (kg == 0) ? od : -3.0e38f;
    PD[0] = fmaxf(PD[0], od2);
    #pragma unroll
    for (int t2 = 0; t2 < 11; ++t2) {
      float a = PD[t2], c2 = PD[t2+1];
      PD[t2] = fminf(a, c2); PD[t2+1] = fmaxf(a, c2);
    }
  }
  if (kg == 0) {
    size_t base = ((size_t)(b*NN + row)*2 + half)*12;
    #pragma unroll
    for (int t = 0; t < 12; ++t)
      idx12[base + t] = cbase + (int)(__float_as_uint(PD[t]) & 0x7FFu);
  }
}

// ---- tier-2: exact fp32 refine of the 24 survivors -> top-9 (r16-validated, 125.8us) ----
__global__ __launch_bounds__(256) void k_refine(const ushortT* __restrict__ fhi_,
    const ushortT* __restrict__ flo_, const float* __restrict__ sqh,
    const int* __restrict__ idx12, int* __restrict__ idxg) {
  int id = blockIdx.x;
  int b = id & 7, rq = id >> 3;
  int w = threadIdx.x >> 6, lane = threadIdx.x & 63;
  int row = rq*4 + w;
  const ushortT* FHb = fhi_ + (size_t)b*NN*CC;
  const ushortT* FLb = flo_ + (size_t)b*NN*CC;
  float rv[3];
  #pragma unroll
  for (int t = 0; t < 3; ++t) {
    int c = lane + 64*t;
    rv[t] = f16tof(FHb[(size_t)row*CC + c]) + f16tof(FLb[(size_t)row*CC + c])*2.44140625e-4f;
  }
  const int* JP = idx12 + (size_t)(b*NN + row)*24;
  float TD[9]; int TI[9];
  #pragma unroll
  for (int t = 0; t < 9; ++t) { TD[t] = -3.0e38f; TI[t] = 0x7fffffff; }
  #pragma unroll
  for (int g = 0; g < 4; ++g) {
    int J6[6]; float s6[6];
    #pragma unroll
    for (int e = 0; e < 6; ++e) J6[e] = JP[g*6 + e];
    #pragma unroll
    for (int e = 0; e < 6; ++e) {
      int j = J6[e];
      float s = 0.f;
      #pragma unroll
      for (int t = 0; t < 3; ++t) {
        int c = lane + 64*t;
        float cv = f16tof(FHb[(size_t)j*CC + c]) + f16tof(FLb[(size_t)j*CC + c])*2.44140625e-4f;
        s = fmaf(rv[t], cv, s);
      }
      s6[e] = s;
    }
    #pragma unroll
    for (int o = 32; o; o >>= 1) {
      #pragma unroll
      for (int e = 0; e < 6; ++e) s6[e] += __shfl_xor(s6[e], o);
    }
    #pragma unroll
    for (int e = 0; e < 6; ++e) {
      int j = J6[e];
      float d = s6[e] - sqh[(size_t)b*NN + j];
      bool ins = (d > TD[0]) || (d == TD[0] && j < TI[0]);
      if (ins) {   // wave-uniform branch
        TD[0] = d; TI[0] = j;
        #pragma unroll
        for (int t = 0; t < 8; ++t) {
          bool sw = (TD[t] > TD[t+1]) || (TD[t] == TD[t+1] && TI[t] < TI[t+1]);
          if (sw) {
            float td = TD[t]; TD[t] = TD[t+1]; TD[t+1] = td;
            int ti = TI[t]; TI[t] = TI[t+1]; TI[t+1] = ti;
          }
        }
      }
    }
  }
  if (lane == 0) {
    size_t base = (size_t)(b*NN + row)*KNN;
    #pragma unroll
    for (int t = 0; t < KNN; ++t) idxg[base + t] = TI[t];
  }
}

// ---- gather neighbors, rel = max_k h[idx_k] - h, interleave fp32 feat ----
__global__ __launch_bounds__(256) void k_gather(const float* __restrict__ h,
    const int* __restrict__ idxg, float* __restrict__ feat) {
  int w = threadIdx.x >> 6, lane = threadIdx.x & 63;
  size_t rg = (size_t)blockIdx.x*4 + w;
  int b = (int)(rg / NN);
  int n = (int)(rg % NN);
  const float* hb = h + (size_t)b*NN*CC;
  int j[KNN];
  #pragma unroll
  for (int t = 0; t < KNN; ++t) j[t] = idxg[rg*KNN + t];
  float2* featp = (float2*)feat;
  #pragma unroll
  for (int t = 0; t < 3; ++t) {
    int c = lane + 64*t;
    float self = hb[(size_t)n*CC + c];
    float m = -3.0e38f;
    #pragma unroll
    for (int k = 0; k < KNN; ++k) m = fmaxf(m, hb[(size_t)j[k]*CC + c]);
    featp[rg*CC + c] = make_float2(self, m - self);
  }
}

// ---- grouped conv via f16-split MFMA; fp32 feat in, B-frags converted on the fly; in-place y ----
__global__ __launch_bounds__(256) void k_gconv(float* __restrict__ feat,
    const ushortT* __restrict__ wgh, const ushortT* __restrict__ wgl,
    const float* __restrict__ bgc, float* __restrict__ y) {
  int rt = blockIdx.x, g = blockIdx.y;
  int tid = threadIdx.x, w = tid >> 6, lane = tid & 63;
  int l15 = lane & 15, kg = lane >> 4;
  int row = rt*64 + w*16 + l15;
  const float4* F4 = (const float4*)feat;
  const f16x8* AH  = (const f16x8*)wgh;    // weight row (g*96+o), stride 12 units
  const f16x8* AL  = (const f16x8*)wgl;
  f16x8 Bh[3], Bl[3];
  #pragma unroll
  for (int ks = 0; ks < 3; ++ks) {
    float4 v0 = F4[(size_t)row*96 + g*24 + ks*8 + kg*2];
    float4 v1 = F4[(size_t)row*96 + g*24 + ks*8 + kg*2 + 1];
    float vv[8] = {v0.x,v0.y,v0.z,v0.w,v1.x,v1.y,v1.z,v1.w};
    split8(vv, Bh[ks], Bl[ks]);
  }
  #pragma unroll 3
  for (int nt = 0; nt < 6; ++nt) {
    f32x4 hh = {0.f,0.f,0.f,0.f}, hl = {0.f,0.f,0.f,0.f}, lh = {0.f,0.f,0.f,0.f};
    #pragma unroll
    for (int ks = 0; ks < 3; ++ks) {
      size_t au = (size_t)(g*GI + nt*16 + l15)*12 + ks*4 + kg;
      f16x8 Ah = AH[au], Al = AL[au];
      hh = __builtin_amdgcn_mfma_f32_16x16x32_f16(Ah, Bh[ks], hh, 0, 0, 0);
      hl = __builtin_amdgcn_mfma_f32_16x16x32_f16(Ah, Bl[ks], hl, 0, 0, 0);
      lh = __builtin_amdgcn_mfma_f32_16x16x32_f16(Al, Bh[ks], lh, 0, 0, 0);
    }
    float4 bias = ((const float4*)bgc)[g*24 + nt*4 + kg];
    float bb[4] = {bias.x, bias.y, bias.z, bias.w};
    float ov[4];
    #pragma unroll
    for (int r = 0; r < 4; ++r)
      ov[r] = fmaf(hl[r] + lh[r], 2.44140625e-4f, hh[r]) + bb[r];
    float4 o; o.x = ov[0]; o.y = ov[1]; o.z = ov[2]; o.w = ov[3];
    ((float4*)y)[(size_t)row*96 + g*24 + nt*4 + kg] = o;
  }
}

// ---- bn + exact gelu: read fp32 y, emit full-size f16 hi/lo packs for fc2 ----
__global__ void k_bn_gelu(const float* __restrict__ y, ushortT* __restrict__ y2hi,
    ushortT* __restrict__ y2lo, const float* __restrict__ scale,
    const float* __restrict__ shift) {
  size_t i = (size_t)blockIdx.x*blockDim.x + threadIdx.x;  // float4 index
  float4 v = ((const float4*)y)[i];
  int c4 = (int)(i % 96);
  float4 sc = ((const float4*)scale)[c4], sh = ((const float4*)shift)[c4];
  float vv[4] = {v.x*sc.x+sh.x, v.y*sc.y+sh.y, v.z*sc.z+sh.z, v.w*sc.w+sh.w};
  ushortT hb[4], lb[4];
  #pragma unroll
  for (int t = 0; t < 4; ++t) {
    float g = 0.5f*vv[t]*(1.0f + erff(vv[t]*0.70710678118654752440f));
    _Float16 hh = (_Float16)g;
    float r = g - (float)hh;
    hb[t] = f16b(hh); lb[t] = f16b((_Float16)(r*4096.f));
  }
  ((uint2*)y2hi)[i] = make_uint2((uintT)hb[0] | ((uintT)hb[1]<<16), (uintT)hb[2] | ((uintT)hb[3]<<16));
  ((uint2*)y2lo)[i] = make_uint2((uintT)lb[0] | ((uintT)lb[1]<<16), (uintT)lb[2] | ((uintT)lb[3]<<16));
}

// ---- fc2 via f16-split MFMA ----
__global__ __launch_bounds__(256) void k_fc2(const ushortT* __restrict__ y2hi,
    const ushortT* __restrict__ y2lo, const ushortT* __restrict__ w2h,
    const ushortT* __restrict__ w2l, const float* __restrict__ b2, float* __restrict__ op) {
  int rt = blockIdx.x;
  int tid = threadIdx.x, w = tid >> 6, lane = tid & 63;
  int l15 = lane & 15, kg = lane >> 4;
  int row = rt*64 + w*16 + l15;
  const f16x8* YH = (const f16x8*)y2hi;   // row stride 48 units
  const f16x8* YL = (const f16x8*)y2lo;
  const f16x8* AH = (const f16x8*)w2h;    // row (out-col) stride 48 units
  const f16x8* AL = (const f16x8*)w2l;
  f16x8 Bh[12], Bl[12];
  #pragma unroll
  for (int ks = 0; ks < 12; ++ks) {
    size_t u = (size_t)row*48 + ks*4 + kg;
    Bh[ks] = YH[u]; Bl[ks] = YL[u];
  }
  #pragma unroll 4
  for (int nt = 0; nt < 12; ++nt) {
    f32x4 hh = {0.f,0.f,0.f,0.f}, hl = {0.f,0.f,0.f,0.f}, lh = {0.f,0.f,0.f,0.f};
    #pragma unroll
    for (int ks = 0; ks < 12; ++ks) {
      size_t au = (size_t)(nt*16 + l15)*48 + ks*4 + kg;
      f16x8 Ah = AH[au], Al = AL[au];
      hh = __builtin_amdgcn_mfma_f32_16x16x32_f16(Ah, Bh[ks], hh, 0, 0, 0);
      hl = __builtin_amdgcn_mfma_f32_16x16x32_f16(Ah, Bl[ks], hl, 0, 0, 0);
      lh = __builtin_amdgcn_mfma_f32_16x16x32_f16(Al, Bh[ks], lh, 0, 0, 0);
    }
    float4 bias = ((const float4*)b2)[nt*4 + kg];
    float bb[4] = {bias.x, bias.y, bias.z, bias.w};
    float ov[4];
    #pragma unroll
    for (int r = 0; r < 4; ++r)
      ov[r] = fmaf(hl[r] + lh[r], 2.44140625e-4f, hh[r]) + bb[r];
    float4 o; o.x = ov[0]; o.y = ov[1]; o.z = ov[2]; o.w = ov[3];
    ((float4*)op)[(size_t)row*48 + nt*4 + kg] = o;
  }
}

// ---------------- final bn + residual + transpose to (B,C,N) ----------------
__global__ __launch_bounds__(256) void k_final(const float* __restrict__ op,
    const float* __restrict__ x, const float* __restrict__ scale,
    const float* __restrict__ shift, float* __restrict__ out) {
  __shared__ float t[32][33];
  int n0 = blockIdx.x*32, c0 = blockIdx.y*32, b = blockIdx.z;
  int tx = threadIdx.x, ty = threadIdx.y;
  #pragma unroll
  for (int s = 0; s < 4; ++s) {
    int r = ty + 8*s;
    int c = c0 + tx;
    t[r][tx] = op[((size_t)b*NN + n0 + r)*CC + c]*scale[c] + shift[c];
  }
  __syncthreads();
  #pragma unroll
  for (int s = 0; s < 4; ++s) {
    int c = ty + 8*s;
    size_t o = ((size_t)b*CC + c0 + c)*NN + n0 + tx;
    out[o] = t[tx][c] + x[o];
  }
}

extern "C" void kernel_launch(void* const* d_in, const int* in_sizes, int n_in,
                              void* d_out, int out_size, void* d_ws, size_t ws_size,
                              hipStream_t stream) {
  (void)in_sizes; (void)n_in; (void)out_size; (void)ws_size;
  const float* x   = (const float*)d_in[0];
  const float* w1  = (const float*)d_in[1];
  const float* b1  = (const float*)d_in[2];
  const float* g1  = (const float*)d_in[3];
  const float* be1 = (const float*)d_in[4];
  const float* wgc = (const float*)d_in[5];
  const float* bgc = (const float*)d_in[6];
  const float* g2  = (const float*)d_in[7];
  const float* be2 = (const float*)d_in[8];
  const float* w2  = (const float*)d_in[9];
  const float* b2  = (const float*)d_in[10];
  const float* g3  = (const float*)d_in[11];
  const float* be3 = (const float*)d_in[12];
  float* ws = (float*)d_ws;

  // Workspace layout (floats) — identical to rounds 15/16:
  float* h      = ws;
  ushortT* fhi  = (ushortT*)(ws + 4816896);
  ushortT* flo  = (ushortT*)(ws + 7225344);
  float* feat   = ws + 4816896;
  float* y      = feat;                        // in-place
  ushortT* y2hi = (ushortT*)ws;                // A
  ushortT* y2lo = (ushortT*)(ws + 14450688);   // C
  float* op     = ws + 4816896;
  float* sqh    = ws + 14450688;
  int*   idxg   = (int*)(ws + 14475776);
  int*   idx12  = (int*)(ws + 14701568);       // ends 15303680 < 19267584
  float* st     = ws + 19267584;               // 1536
  float* part   = ws + 19269120;               // 196608
  ushortT* w2h  = (ushortT*)(ws + 19465728);   // 73728 ushorts
  ushortT* w2l  = (ushortT*)(ws + 19502592);
  ushortT* wgh  = (ushortT*)(ws + 19539456);   // 36864 ushorts
  ushortT* wgl  = (ushortT*)(ws + 19557888);   // end 19576320 floats = 78.3 MB
  float* sc1 = st;        float* sh1 = st + 192;
  float* sc2 = st + 384;  float* sh2 = st + 768;
  float* sc3 = st + 1152; float* sh3 = st + 1344;
  float* out = (float*)d_out;

  k_packw2<<<108, 256, 0, stream>>>(w2, wgc, w2h, w2l, wgh, wgl);
  k_fc1<<<dim3(49,3,8), 256, 0, stream>>>(x, w1, b1, h);
  k_stats_part<<<NCHUNK, CC, 0, stream>>>(h, CC, part);
  k_stats_fin<<<CC, 256, 0, stream>>>(part, CC, g1, be1, sc1, sh1);
  k_h_f<<<NR/4, 256, 0, stream>>>(h, fhi, flo, sqh, sc1, sh1);
  k_knn12<<<dim3(784), 256, 0, stream>>>(fhi, sqh, idx12);
  k_refine<<<dim3(6272), 256, 0, stream>>>(fhi, flo, sqh, idx12, idxg);
  k_gather<<<NR/4, 256, 0, stream>>>(h, idxg, feat);
  k_gconv<<<dim3(392,4), 256, 0, stream>>>(feat, wgh, wgl, bgc, y);   // in-place
  k_stats_part<<<NCHUNK, C2, 0, stream>>>(y, C2, part);
  k_stats_fin<<<C2, 256, 0, stream>>>(part, C2, g2, be2, sc2, sh2);
  k_bn_gelu<<<9408, 256, 0, stream>>>(y, y2hi, y2lo, sc2, sh2);
  k_fc2<<<392, 256, 0, stream>>>(y2hi, y2lo, w2h, w2l, b2, op);
  k_stats_part<<<NCHUNK, CC, 0, stream>>>(op, CC, part);
  k_stats_fin<<<CC, 256, 0, stream>>>(part, CC, g3, be3, sc3, sh3);
  k_final<<<dim3(98,6,8), dim3(32,8), 0, stream>>>(op, x, sc3, sh3, out);
}